// Round 11
// baseline (62.717 us; speedup 1.0000x reference)
//
#include <hip/hip_runtime.h>

#define TEX_H 256
#define TEX_W 256
#define FCH 16
#define NPIX (8 * 256 * 256)
#define PPG 4                 // pixels per 16-lane group (software pipeline depth)

#define SQRT2_F 1.41421356237f
// Interior weights (grid anchored at u-2 => du,dv exactly in {0,1,2};
// d=2 slots fail w>0.1, leaving the 3x3 with constant weights):
#define W_EDGE   0.24311673443f   // exp(-sqrt(2))
#define W_DIAG   0.13533528324f   // exp(-2)

// Workspace layout (total 4,595,712 B):
#define HALO_C_OFF 0
#define HALO_N_OFF (256 * 256 * 16)
#define DIR_C_OFF  (HALO_N_OFF + 256 * 256)
#define DIR_W_OFF  (DIR_C_OFF + 2 * 4 * 256 * 16)
#define WS_FLOATS  (DIR_W_OFF + 2 * 4 * 256)

// 16 lanes per pixel-group (one per channel), PPG pixels per group, strided by
// NPIX/PPG so each slot's loads stay coalesced across consecutive groups.
// Phase 1: issue all mask+uv loads (independent). Phase 2: issue f loads for
// masked pixels (independent). Phase 3: atomics. Interior pixel = 1 atomic per
// channel into its center cell (+count on lane 0); weighting deferred to the
// finalize conv. Boundary (u<2 or v<2): exact expf path into edge strips.
__global__ __launch_bounds__(256) void splat_kernel(
    const float*  __restrict__ f_map,
    const float2* __restrict__ uv_map,
    const float*  __restrict__ mask,
    float* __restrict__ ws)
{
    const int G = NPIX / PPG;                       // group-stride in pixels
    int gid = blockIdx.x * 16 + (threadIdx.x >> 4); // 16-lane group id
    int c   = threadIdx.x & 15;

    float  m[PPG];
    float2 uv[PPG];
    #pragma unroll
    for (int k = 0; k < PPG; ++k) {
        int pix = gid + k * G;
        m[k]  = mask[pix];
        uv[k] = uv_map[pix];
    }

    float f[PPG];
    #pragma unroll
    for (int k = 0; k < PPG; ++k) {
        if (m[k] != 0.0f) f[k] = f_map[(gid + k * G) * FCH + c];
    }

    #pragma unroll
    for (int k = 0; k < PPG; ++k) {
        if (m[k] == 0.0f) continue;
        float u = uv[k].x * 256.0f;
        float v = uv[k].y * 256.0f;
        float fv = f[k];

        if (u >= 2.0f && v >= 2.0f) {
            int iu = (int)u, iv = (int)v;           // center cell (uv < 1 => <=255)
            unsafeAtomicAdd(&ws[HALO_C_OFF + (iv * 256 + iu) * FCH + c], fv);
            if (c == 0) unsafeAtomicAdd(&ws[HALO_N_OFF + iv * 256 + iu], 1.0f);
        } else {
            // Exact reference path; passing slots have ui<4 (u<2) or vi<4.
            float us = fmaxf(u - 2.0f, 0.0f);
            float vs = fmaxf(v - 2.0f, 0.0f);
            #pragma unroll
            for (int kv = 0; kv < 4; ++kv) {
                float vg = vs + (float)kv;
                int vi = (int)vg;
                float dvf = fabsf(vg - v);
                #pragma unroll
                for (int ku = 0; ku < 4; ++ku) {
                    float ug = us + (float)ku;
                    int ui = (int)ug;
                    float duf = fabsf(ug - u);
                    float w = expf(-sqrtf(duf * duf + dvf * dvf) * SQRT2_F);
                    if (w > 0.1f && vi < TEX_H && ui < TEX_W) {
                        int cell = (ui < 4) ? (ui * 256 + vi)        // region 0
                                            : ((4 + vi) * 256 + ui); // region 1
                        unsafeAtomicAdd(&ws[DIR_C_OFF + cell * FCH + c], w * fv);
                        if (c == 0) unsafeAtomicAdd(&ws[DIR_W_OFF + cell], w);
                    }
                }
            }
        }
    }
}

// 1024 WGs x 256 threads; WG = 8x8 texel tile; thread = (texel 0..63, c4 0..3).
// csum(texel) = 3x3 const-weight conv of per-center sums (+ boundary strip);
// wsum analogous with counts. Normalize, write 8 broadcast copies.
__global__ __launch_bounds__(256) void finalize_kernel(
    const float* __restrict__ ws,
    float* __restrict__ out)
{
    int tile = blockIdx.x;                  // 32x32 tiles of 8x8
    int r0 = (tile >> 5) << 3;
    int c0 = (tile & 31) << 3;
    int tx = threadIdx.x >> 2;              // texel in tile 0..63
    int c4 = threadIdx.x & 3;               // float4 chunk 0..3
    int gr = r0 + (tx >> 3);
    int gc = c0 + (tx & 7);

    float4 cs = make_float4(0.f, 0.f, 0.f, 0.f);
    float wsm = 0.0f;

    #pragma unroll
    for (int a = -1; a <= 1; ++a) {
        int cr = gr + a;
        if (cr < 0 || cr > 255) continue;
        #pragma unroll
        for (int b = -1; b <= 1; ++b) {
            int cc = gc + b;
            if (cc < 0 || cc > 255) continue;
            float w = (a == 0 && b == 0) ? 1.0f
                    : ((a == 0 || b == 0) ? W_EDGE : W_DIAG);
            int cell = cr * 256 + cc;
            float4 h = *(const float4*)&ws[HALO_C_OFF + cell * FCH + c4 * 4];
            cs.x += w * h.x; cs.y += w * h.y; cs.z += w * h.z; cs.w += w * h.w;
            wsm  += w * ws[HALO_N_OFF + cell];
        }
    }

    // Boundary strip merge (matches splat's region assignment exactly).
    if (gc < 4) {
        int cell = gc * 256 + gr;
        float4 d = *(const float4*)&ws[DIR_C_OFF + cell * FCH + c4 * 4];
        cs.x += d.x; cs.y += d.y; cs.z += d.z; cs.w += d.w;
        wsm  += ws[DIR_W_OFF + cell];
    } else if (gr < 4) {
        int cell = (4 + gr) * 256 + gc;
        float4 d = *(const float4*)&ws[DIR_C_OFF + cell * FCH + c4 * 4];
        cs.x += d.x; cs.y += d.y; cs.z += d.z; cs.w += d.w;
        wsm  += ws[DIR_W_OFF + cell];
    }

    float s = (wsm > 0.01f) ? (1.0f / (wsm + 0.001f)) : 0.0f;
    cs.x *= s; cs.y *= s; cs.z *= s; cs.w *= s;

    size_t base = ((size_t)gr * 256 + gc) * FCH + c4 * 4;
    #pragma unroll
    for (int b = 0; b < 8; ++b) {
        *(float4*)&out[(size_t)b * (256 * 256 * FCH) + base] = cs;
    }
}

extern "C" void kernel_launch(void* const* d_in, const int* in_sizes, int n_in,
                              void* d_out, int out_size, void* d_ws, size_t ws_size,
                              hipStream_t stream) {
    const float*  f_map  = (const float*)d_in[0];
    const float2* uv_map = (const float2*)d_in[1];
    const float*  mask   = (const float*)d_in[2];
    float* out = (float*)d_out;
    float* ws  = (float*)d_ws;

    hipMemsetAsync(ws, 0, (size_t)WS_FLOATS * sizeof(float), stream);

    // groups total = NPIX/PPG; 16 groups per 256-thread block.
    splat_kernel<<<(NPIX / PPG) / 16, 256, 0, stream>>>(f_map, uv_map, mask, ws);
    finalize_kernel<<<1024, 256, 0, stream>>>(ws, out);
}